// Round 9
// baseline (175.563 us; speedup 1.0000x reference)
//
#include <hip/hip_runtime.h>

// SemanticConditioner: out = canvas + (embeddings @ W^T + residuals)[region_ids]
// B=4, N=65536, D=256, E=1536, R=512  (all fp32)

#define B_DIM 4
#define N_DIM 65536
#define D_DIM 256
#define E_DIM 1536
#define R_DIM 512
#define RPB   4     // embedding rows per block (cond GEMM, full-K)

typedef float f32x4 __attribute__((ext_vector_type(4)));

// ---------------------------------------------------------------------------
// Kernel 1: transpose W [D][E] -> Wt [E][D]
// grid (E/32, D/32) = (48, 8), 256 threads
// ---------------------------------------------------------------------------
__global__ __launch_bounds__(256) void k_transpose(const float* __restrict__ W,
                                                   float* __restrict__ Wt) {
    __shared__ float t[32][33];
    const int eb = blockIdx.x * 32;
    const int db = blockIdx.y * 32;
    const int tx = threadIdx.x & 31;
    const int ty = threadIdx.x >> 5;
#pragma unroll
    for (int j = 0; j < 4; ++j)
        t[ty + 8 * j][tx] = W[(size_t)(db + ty + 8 * j) * E_DIM + eb + tx];
    __syncthreads();
#pragma unroll
    for (int j = 0; j < 4; ++j)
        Wt[(size_t)(eb + ty + 8 * j) * D_DIM + db + tx] = t[tx][ty + 8 * j];
}

// ---------------------------------------------------------------------------
// Kernel 2 (fused full-K, +res): cond[r][d] = sum_e emb[r][e]*Wt[e][d] + res[r][d]
// Replaces split-K k_cond_part + k_reduce: one launch, no 8 MB part round-trip.
// grid R/RPB = 128 blocks, 256 threads; Wt reads are coalesced L2 hits.
// ---------------------------------------------------------------------------
__global__ __launch_bounds__(256) void k_cond(const float* __restrict__ emb,
                                              const float* __restrict__ Wt,
                                              const float* __restrict__ res,
                                              float* __restrict__ cond) {
    __shared__ f32x4 embs[RPB][E_DIM / 4];  // 24 KB
    const int r0 = blockIdx.x * RPB;
    const int d  = threadIdx.x;

    const f32x4* eg = reinterpret_cast<const f32x4*>(emb) + (size_t)r0 * (E_DIM / 4);
#pragma unroll
    for (int t = 0; t < (RPB * E_DIM / 4) / 256; ++t) {  // 6 coalesced float4/thread
        const int f = t * 256 + d;
        embs[f / (E_DIM / 4)][f % (E_DIM / 4)] = eg[f];
    }
    __syncthreads();

    float acc0 = 0.f, acc1 = 0.f, acc2 = 0.f, acc3 = 0.f;
#pragma unroll 8
    for (int g = 0; g < E_DIM / 4; ++g) {
        const f32x4 a0 = embs[0][g];
        const f32x4 a1 = embs[1][g];
        const f32x4 a2 = embs[2][g];
        const f32x4 a3 = embs[3][g];
        const int e = 4 * g;
        const float w0 = Wt[(size_t)(e + 0) * D_DIM + d];
        const float w1 = Wt[(size_t)(e + 1) * D_DIM + d];
        const float w2 = Wt[(size_t)(e + 2) * D_DIM + d];
        const float w3 = Wt[(size_t)(e + 3) * D_DIM + d];
        acc0 += a0.x * w0 + a0.y * w1 + a0.z * w2 + a0.w * w3;
        acc1 += a1.x * w0 + a1.y * w1 + a1.z * w2 + a1.w * w3;
        acc2 += a2.x * w0 + a2.y * w1 + a2.z * w2 + a2.w * w3;
        acc3 += a3.x * w0 + a3.y * w1 + a3.z * w2 + a3.w * w3;
    }
    cond[(size_t)(r0 + 0) * D_DIM + d] = acc0 + res[(size_t)(r0 + 0) * D_DIM + d];
    cond[(size_t)(r0 + 1) * D_DIM + d] = acc1 + res[(size_t)(r0 + 1) * D_DIM + d];
    cond[(size_t)(r0 + 2) * D_DIM + d] = acc2 + res[(size_t)(r0 + 2) * D_DIM + d];
    cond[(size_t)(r0 + 3) * D_DIM + d] = acc3 + res[(size_t)(r0 + 3) * D_DIM + d];
}

// ---------------------------------------------------------------------------
// Kernel 3: out = canvas + cond[region_ids]
// 2-deep rotated software pipeline: stores of group t consume loads issued
// 2 iterations earlier; NT store-acks (in vmcnt order ahead of newer loads)
// get 2 full iterations of slack before any wait can block on them.
// Named registers only (no runtime-indexed arrays -> no scratch).
// Cached canvas loads (L3-resident across replays) + NT stores (no-allocate).
// b-fused: one rid + one cond row per wave serve all B=4 batch rows.
// grid 2048 x 256, 8 groups/thread.
// ---------------------------------------------------------------------------
__global__ __launch_bounds__(256) void k_add(const f32x4* __restrict__ canvas,
                                             const int* __restrict__ rid,
                                             const f32x4* __restrict__ cond,
                                             f32x4* __restrict__ out) {
    const int stride = gridDim.x * blockDim.x;              // 524,288
    const int bstep  = N_DIM * (D_DIM / 4);                 // 4,194,304 float4
    int i = blockIdx.x * blockDim.x + threadIdx.x;          // group 0
    int j = i + stride;                                     // group 1

    // prologue: prefetch groups 0 (A) and 1 (B)
    f32x4 cA0 = canvas[i];
    f32x4 cA1 = canvas[i + bstep];
    f32x4 cA2 = canvas[i + 2 * bstep];
    f32x4 cA3 = canvas[i + 3 * bstep];
    f32x4 aA  = cond[rid[i >> 6] * (D_DIM / 4) + (i & 63)];
    f32x4 cB0 = canvas[j];
    f32x4 cB1 = canvas[j + bstep];
    f32x4 cB2 = canvas[j + 2 * bstep];
    f32x4 cB3 = canvas[j + 3 * bstep];
    f32x4 aB  = cond[rid[j >> 6] * (D_DIM / 4) + (j & 63)];

#pragma unroll 1
    for (int it = 0; it < 6; ++it) {
        const int k = j + stride;
        // prefetch group t+2 first (maximum slack before its first use)
        const int   rC = rid[k >> 6];
        const f32x4 n0 = canvas[k];
        const f32x4 n1 = canvas[k + bstep];
        const f32x4 n2 = canvas[k + 2 * bstep];
        const f32x4 n3 = canvas[k + 3 * bstep];
        const f32x4 na = cond[rC * (D_DIM / 4) + (k & 63)];
        // store group t (its loads are 2 iterations old)
        __builtin_nontemporal_store(cA0 + aA, &out[i]);
        __builtin_nontemporal_store(cA1 + aA, &out[i + bstep]);
        __builtin_nontemporal_store(cA2 + aA, &out[i + 2 * bstep]);
        __builtin_nontemporal_store(cA3 + aA, &out[i + 3 * bstep]);
        // rotate A <- B <- C
        cA0 = cB0; cA1 = cB1; cA2 = cB2; cA3 = cB3; aA = aB;
        cB0 = n0;  cB1 = n1;  cB2 = n2;  cB3 = n3;  aB = na;
        i = j; j = k;
    }
    // epilogue: groups 6 and 7
    __builtin_nontemporal_store(cA0 + aA, &out[i]);
    __builtin_nontemporal_store(cA1 + aA, &out[i + bstep]);
    __builtin_nontemporal_store(cA2 + aA, &out[i + 2 * bstep]);
    __builtin_nontemporal_store(cA3 + aA, &out[i + 3 * bstep]);
    __builtin_nontemporal_store(cB0 + aB, &out[j]);
    __builtin_nontemporal_store(cB1 + aB, &out[j + bstep]);
    __builtin_nontemporal_store(cB2 + aB, &out[j + 2 * bstep]);
    __builtin_nontemporal_store(cB3 + aB, &out[j + 3 * bstep]);
}

// ---------------------------------------------------------------------------
extern "C" void kernel_launch(void* const* d_in, const int* in_sizes, int n_in,
                              void* d_out, int out_size, void* d_ws, size_t ws_size,
                              hipStream_t stream) {
    const float* canvas = (const float*)d_in[0];  // [B,N,D]
    const float* emb    = (const float*)d_in[1];  // [R,E]
    const float* W      = (const float*)d_in[2];  // [D,E]
    const float* res    = (const float*)d_in[3];  // [R,D]
    const int*   rid    = (const int*)d_in[4];    // [N]

    // ws layout: Wt (E*D fp32 = 1.5 MB) | cond (R*D fp32 = 0.5 MB)
    float* Wt   = (float*)d_ws;
    float* cond = Wt + (size_t)E_DIM * D_DIM;

    dim3 tgrid(E_DIM / 32, D_DIM / 32);
    k_transpose<<<tgrid, 256, 0, stream>>>(W, Wt);
    k_cond<<<R_DIM / RPB, 256, 0, stream>>>(emb, Wt, res, cond);
    k_add<<<2048, 256, 0, stream>>>((const f32x4*)canvas, rid,
                                    (const f32x4*)cond, (f32x4*)d_out);
}

// Round 10
// 126.820 us; speedup vs baseline: 1.3844x; 1.3844x over previous
//
#include <hip/hip_runtime.h>

// SemanticConditioner: out = canvas + (embeddings @ W^T + residuals)[region_ids]
// B=4, N=65536, D=256, E=1536, R=512  (all fp32)

#define B_DIM 4
#define N_DIM 65536
#define D_DIM 256
#define E_DIM 1536
#define R_DIM 512
#define RPB   4     // embedding rows per block (cond GEMM)
#define KS    4     // K-splits (cond GEMM)
#define KSUB  (E_DIM / KS)      // 384
#define KSUB4 (KSUB / 4)        // 96

typedef float f32x4 __attribute__((ext_vector_type(4)));

// ---------------------------------------------------------------------------
// Kernel 1: transpose W [D][E] -> Wt [E][D]
// grid (E/32, D/32) = (48, 8), 256 threads
// ---------------------------------------------------------------------------
__global__ __launch_bounds__(256) void k_transpose(const float* __restrict__ W,
                                                   float* __restrict__ Wt) {
    __shared__ float t[32][33];
    const int eb = blockIdx.x * 32;
    const int db = blockIdx.y * 32;
    const int tx = threadIdx.x & 31;
    const int ty = threadIdx.x >> 5;
#pragma unroll
    for (int j = 0; j < 4; ++j)
        t[ty + 8 * j][tx] = W[(size_t)(db + ty + 8 * j) * E_DIM + eb + tx];
    __syncthreads();
#pragma unroll
    for (int j = 0; j < 4; ++j)
        Wt[(size_t)(eb + ty + 8 * j) * D_DIM + db + tx] = t[tx][ty + 8 * j];
}

// ---------------------------------------------------------------------------
// Kernel 2: partial GEMM  part[ks][r][d] = sum_{e in ks-chunk} emb[r][e]*Wt[e][d]
// grid (R/RPB, KS) = (128, 4) = 512 blocks (2/CU), 256 threads
// ---------------------------------------------------------------------------
__global__ __launch_bounds__(256) void k_cond_part(const float* __restrict__ emb,
                                                   const float* __restrict__ Wt,
                                                   float* __restrict__ part) {
    __shared__ f32x4 embs[RPB][KSUB4];  // 6 KB
    const int r0 = blockIdx.x * RPB;
    const int ks = blockIdx.y;
    const int d  = threadIdx.x;

    const f32x4* eg = reinterpret_cast<const f32x4*>(emb);
    for (int f = d; f < RPB * KSUB4; f += 256) {
        const int rr = f / KSUB4, gg = f % KSUB4;
        embs[rr][gg] = eg[(size_t)(r0 + rr) * (E_DIM / 4) + ks * KSUB4 + gg];
    }
    __syncthreads();

    float acc0 = 0.f, acc1 = 0.f, acc2 = 0.f, acc3 = 0.f;
    const int ebase = ks * KSUB;
#pragma unroll 8
    for (int g = 0; g < KSUB4; ++g) {
        const f32x4 a0 = embs[0][g];
        const f32x4 a1 = embs[1][g];
        const f32x4 a2 = embs[2][g];
        const f32x4 a3 = embs[3][g];
        const int e = ebase + 4 * g;
        const float w0 = Wt[(size_t)(e + 0) * D_DIM + d];
        const float w1 = Wt[(size_t)(e + 1) * D_DIM + d];
        const float w2 = Wt[(size_t)(e + 2) * D_DIM + d];
        const float w3 = Wt[(size_t)(e + 3) * D_DIM + d];
        acc0 += a0.x * w0 + a0.y * w1 + a0.z * w2 + a0.w * w3;
        acc1 += a1.x * w0 + a1.y * w1 + a1.z * w2 + a1.w * w3;
        acc2 += a2.x * w0 + a2.y * w1 + a2.z * w2 + a2.w * w3;
        acc3 += a3.x * w0 + a3.y * w1 + a3.z * w2 + a3.w * w3;
    }
    float* p = part + ((size_t)ks * R_DIM + r0) * D_DIM + d;
    p[0 * D_DIM] = acc0;
    p[1 * D_DIM] = acc1;
    p[2 * D_DIM] = acc2;
    p[3 * D_DIM] = acc3;
}

// ---------------------------------------------------------------------------
// Kernel 3: cond[r][d] = sum_ks part[ks][r][d] + res[r][d]
// grid R*D/256 = 512 blocks, 256 threads
// ---------------------------------------------------------------------------
__global__ __launch_bounds__(256) void k_reduce(const float* __restrict__ part,
                                                const float* __restrict__ res,
                                                float* __restrict__ cond) {
    const int i = blockIdx.x * 256 + threadIdx.x;  // r*D + d
    const size_t stride = (size_t)R_DIM * D_DIM;
    cond[i] = part[i] + part[i + stride] + part[i + 2 * stride] +
              part[i + 3 * stride] + res[i];
}

// ---------------------------------------------------------------------------
// Kernel 4: out = canvas + cond[region_ids]
// A/B this round (vs R7, single variable): grid 2048 -> 8192 blocks, loop
// 8 -> 2 groups/thread. R7 counters showed VALUBusy 2%, Occupancy 53-58% ->
// latency-bound with an under-filled wave pool; 4x the block pool gives the
// scheduler more resident waves to rotate during vmcnt waits.
// Cached canvas loads (L3-resident across replays) + NT stores (no-allocate).
// b-fused: one rid + one cond row per wave serve all B=4 batch rows.
// ---------------------------------------------------------------------------
__global__ __launch_bounds__(256) void k_add(const f32x4* __restrict__ canvas,
                                             const int* __restrict__ rid,
                                             const f32x4* __restrict__ cond,
                                             f32x4* __restrict__ out) {
    const int stride = gridDim.x * blockDim.x;              // 2,097,152
    const int bstep  = N_DIM * (D_DIM / 4);                 // 4,194,304 float4
    int i = blockIdx.x * blockDim.x + threadIdx.x;          // n*64 + d4
    // N*D/4 = 4,194,304 = 2 * stride (exact)
#pragma unroll 1
    for (int it = 0; it < 2; ++it, i += stride) {
        const f32x4 c0 = canvas[i];
        const f32x4 c1 = canvas[i + bstep];
        const f32x4 c2 = canvas[i + 2 * bstep];
        const f32x4 c3 = canvas[i + 3 * bstep];
        const int n  = i >> 6;          // wave-uniform
        const int d4 = i & 63;
        const int r  = rid[n];          // wave-uniform, L1/L2
        const f32x4 a = cond[r * (D_DIM / 4) + d4];  // coalesced 1 KB row, L2
        __builtin_nontemporal_store(c0 + a, &out[i]);
        __builtin_nontemporal_store(c1 + a, &out[i + bstep]);
        __builtin_nontemporal_store(c2 + a, &out[i + 2 * bstep]);
        __builtin_nontemporal_store(c3 + a, &out[i + 3 * bstep]);
    }
}

// ---------------------------------------------------------------------------
extern "C" void kernel_launch(void* const* d_in, const int* in_sizes, int n_in,
                              void* d_out, int out_size, void* d_ws, size_t ws_size,
                              hipStream_t stream) {
    const float* canvas = (const float*)d_in[0];  // [B,N,D]
    const float* emb    = (const float*)d_in[1];  // [R,E]
    const float* W      = (const float*)d_in[2];  // [D,E]
    const float* res    = (const float*)d_in[3];  // [R,D]
    const int*   rid    = (const int*)d_in[4];    // [N]

    // ws layout: Wt (E*D) | part (KS*R*D) | cond (R*D)   -- all fp32
    float* Wt   = (float*)d_ws;
    float* part = Wt + (size_t)E_DIM * D_DIM;
    float* cond = part + (size_t)KS * R_DIM * D_DIM;

    dim3 tgrid(E_DIM / 32, D_DIM / 32);
    k_transpose<<<tgrid, 256, 0, stream>>>(W, Wt);
    dim3 cgrid(R_DIM / RPB, KS);
    k_cond_part<<<cgrid, 256, 0, stream>>>(emb, Wt, part);
    k_reduce<<<(R_DIM * D_DIM) / 256, 256, 0, stream>>>(part, res, cond);
    k_add<<<8192, 256, 0, stream>>>((const f32x4*)canvas, rid,
                                    (const f32x4*)cond, (f32x4*)d_out);
}

// Round 11
// 115.821 us; speedup vs baseline: 1.5158x; 1.0950x over previous
//
#include <hip/hip_runtime.h>

// SemanticConditioner: out = canvas + (embeddings @ W^T + residuals)[region_ids]
// B=4, N=65536, D=256, E=1536, R=512  (all fp32)

#define B_DIM 4
#define N_DIM 65536
#define D_DIM 256
#define E_DIM 1536
#define R_DIM 512
#define RPB   8     // embedding rows per block (cond GEMM)
#define KS    8     // K-splits (cond GEMM)
#define KSUB  (E_DIM / KS)      // 192
#define KSUB4 (KSUB / 4)        // 48

typedef float f32x4 __attribute__((ext_vector_type(4)));

// ---------------------------------------------------------------------------
// Kernel 1: transpose W [D][E] -> Wt [E][D]
// grid (E/32, D/32) = (48, 8), 256 threads
// ---------------------------------------------------------------------------
__global__ __launch_bounds__(256) void k_transpose(const float* __restrict__ W,
                                                   float* __restrict__ Wt) {
    __shared__ float t[32][33];
    const int eb = blockIdx.x * 32;
    const int db = blockIdx.y * 32;
    const int tx = threadIdx.x & 31;
    const int ty = threadIdx.x >> 5;
#pragma unroll
    for (int j = 0; j < 4; ++j)
        t[ty + 8 * j][tx] = W[(size_t)(db + ty + 8 * j) * E_DIM + eb + tx];
    __syncthreads();
#pragma unroll
    for (int j = 0; j < 4; ++j)
        Wt[(size_t)(eb + ty + 8 * j) * D_DIM + db + tx] = t[tx][ty + 8 * j];
}

// ---------------------------------------------------------------------------
// Kernel 2: partial GEMM  part[ks][r][d] = sum_{e in ks-chunk} emb[r][e]*Wt[e][d]
// RPB=8/KS=8: same 512-block parallelism as before, but each block covers
// 8 r-rows -> Wt L2 re-read traffic halved (196 -> 98 MB).
// grid (R/RPB, KS) = (64, 8) = 512 blocks, 256 threads
// ---------------------------------------------------------------------------
__global__ __launch_bounds__(256) void k_cond_part(const float* __restrict__ emb,
                                                   const float* __restrict__ Wt,
                                                   float* __restrict__ part) {
    __shared__ f32x4 embs[RPB][KSUB4];  // 6 KB
    const int r0 = blockIdx.x * RPB;
    const int ks = blockIdx.y;
    const int d  = threadIdx.x;

    const f32x4* eg = reinterpret_cast<const f32x4*>(emb);
    for (int f = d; f < RPB * KSUB4; f += 256) {
        const int rr = f / KSUB4, gg = f % KSUB4;
        embs[rr][gg] = eg[(size_t)(r0 + rr) * (E_DIM / 4) + ks * KSUB4 + gg];
    }
    __syncthreads();

    float a0 = 0.f, a1 = 0.f, a2 = 0.f, a3 = 0.f;
    float a4 = 0.f, a5 = 0.f, a6 = 0.f, a7 = 0.f;
    const int ebase = ks * KSUB;
#pragma unroll 4
    for (int g = 0; g < KSUB4; ++g) {
        const int e = ebase + 4 * g;
        const float w0 = Wt[(size_t)(e + 0) * D_DIM + d];
        const float w1 = Wt[(size_t)(e + 1) * D_DIM + d];
        const float w2 = Wt[(size_t)(e + 2) * D_DIM + d];
        const float w3 = Wt[(size_t)(e + 3) * D_DIM + d];
        {
            const f32x4 v = embs[0][g];
            a0 += v.x * w0 + v.y * w1 + v.z * w2 + v.w * w3;
        }
        {
            const f32x4 v = embs[1][g];
            a1 += v.x * w0 + v.y * w1 + v.z * w2 + v.w * w3;
        }
        {
            const f32x4 v = embs[2][g];
            a2 += v.x * w0 + v.y * w1 + v.z * w2 + v.w * w3;
        }
        {
            const f32x4 v = embs[3][g];
            a3 += v.x * w0 + v.y * w1 + v.z * w2 + v.w * w3;
        }
        {
            const f32x4 v = embs[4][g];
            a4 += v.x * w0 + v.y * w1 + v.z * w2 + v.w * w3;
        }
        {
            const f32x4 v = embs[5][g];
            a5 += v.x * w0 + v.y * w1 + v.z * w2 + v.w * w3;
        }
        {
            const f32x4 v = embs[6][g];
            a6 += v.x * w0 + v.y * w1 + v.z * w2 + v.w * w3;
        }
        {
            const f32x4 v = embs[7][g];
            a7 += v.x * w0 + v.y * w1 + v.z * w2 + v.w * w3;
        }
    }
    float* p = part + ((size_t)ks * R_DIM + r0) * D_DIM + d;
    p[0 * D_DIM] = a0;
    p[1 * D_DIM] = a1;
    p[2 * D_DIM] = a2;
    p[3 * D_DIM] = a3;
    p[4 * D_DIM] = a4;
    p[5 * D_DIM] = a5;
    p[6 * D_DIM] = a6;
    p[7 * D_DIM] = a7;
}

// ---------------------------------------------------------------------------
// Kernel 3: cond[r][d] = sum_ks part[ks][r][d] + res[r][d]
// grid R*D/256 = 512 blocks, 256 threads
// ---------------------------------------------------------------------------
__global__ __launch_bounds__(256) void k_reduce(const float* __restrict__ part,
                                                const float* __restrict__ res,
                                                float* __restrict__ cond) {
    const int i = blockIdx.x * 256 + threadIdx.x;  // r*D + d
    const size_t stride = (size_t)R_DIM * D_DIM;
    float s = res[i];
#pragma unroll
    for (int ks = 0; ks < KS; ++ks)
        s += part[i + ks * stride];
    cond[i] = s;
}

// ---------------------------------------------------------------------------
// Kernel 4: out = canvas + cond[region_ids]
// A/B this round (k_add side): grid 8192 -> 16384, exactly ONE group per
// thread (loop deleted) -> shortest dep chain per wave, maximal block pool.
// Cached canvas loads (L3 absorbs ~45% of reads) + NT stores (no-allocate;
// R5/R7 A/B showed reads are nearly free, stores are the binding side).
// b-fused: one rid + one cond row per wave serve all B=4 batch rows.
// ---------------------------------------------------------------------------
__global__ __launch_bounds__(256) void k_add(const f32x4* __restrict__ canvas,
                                             const int* __restrict__ rid,
                                             const f32x4* __restrict__ cond,
                                             f32x4* __restrict__ out) {
    const int bstep = N_DIM * (D_DIM / 4);                  // 4,194,304 float4
    const int i = blockIdx.x * blockDim.x + threadIdx.x;    // n*64 + d4
    const f32x4 c0 = canvas[i];
    const f32x4 c1 = canvas[i + bstep];
    const f32x4 c2 = canvas[i + 2 * bstep];
    const f32x4 c3 = canvas[i + 3 * bstep];
    const int n  = i >> 6;              // wave-uniform
    const int d4 = i & 63;
    const int r  = rid[n];              // wave-uniform, L1/L2
    const f32x4 a = cond[r * (D_DIM / 4) + d4];  // coalesced 1 KB row, L2
    __builtin_nontemporal_store(c0 + a, &out[i]);
    __builtin_nontemporal_store(c1 + a, &out[i + bstep]);
    __builtin_nontemporal_store(c2 + a, &out[i + 2 * bstep]);
    __builtin_nontemporal_store(c3 + a, &out[i + 3 * bstep]);
}

// ---------------------------------------------------------------------------
extern "C" void kernel_launch(void* const* d_in, const int* in_sizes, int n_in,
                              void* d_out, int out_size, void* d_ws, size_t ws_size,
                              hipStream_t stream) {
    const float* canvas = (const float*)d_in[0];  // [B,N,D]
    const float* emb    = (const float*)d_in[1];  // [R,E]
    const float* W      = (const float*)d_in[2];  // [D,E]
    const float* res    = (const float*)d_in[3];  // [R,D]
    const int*   rid    = (const int*)d_in[4];    // [N]

    // ws layout: Wt (E*D) | part (KS*R*D) | cond (R*D)   -- all fp32
    float* Wt   = (float*)d_ws;
    float* part = Wt + (size_t)E_DIM * D_DIM;
    float* cond = part + (size_t)KS * R_DIM * D_DIM;

    dim3 tgrid(E_DIM / 32, D_DIM / 32);
    k_transpose<<<tgrid, 256, 0, stream>>>(W, Wt);
    dim3 cgrid(R_DIM / RPB, KS);
    k_cond_part<<<cgrid, 256, 0, stream>>>(emb, Wt, part);
    k_reduce<<<(R_DIM * D_DIM) / 256, 256, 0, stream>>>(part, res, cond);
    k_add<<<16384, 256, 0, stream>>>((const f32x4*)canvas, rid,
                                     (const f32x4*)cond, (f32x4*)d_out);
}